// Round 1
// 102.036 us; speedup vs baseline: 1.0013x; 1.0013x over previous
//
#include <hip/hip_runtime.h>
#include <math.h>

// Problem constants (from reference)
#define BB   2
#define LQ   24
#define LK   24
#define NH   4
#define DM   32     // d_model
#define DF   32     // d_feat
#define HW   256    // 16x16
#define NEG  0.1f

// Padded LDS image: 20 rows, pitch 24 floats.
// CHPAD = 480 + 8: the +8 breaks channel-stride bank alignment (480 % 32 == 0
// would put all 4 channel-pair lanes of a strip group in the same bank group).
#define PITCH 24
#define CHPAD (20 * PITCH + 8)   // 488 floats per channel image

#define NIMG (BB * NH * LK)  // 192 head-images

__device__ __forceinline__ float lrelu(float x) { return x >= 0.f ? x : NEG * x; }

// -----------------------------------------------------------------------------
// K1: grid 768 = img * 4 + cg, 256 threads (1 thread/pixel for projections).
// Each block: 8-channel slice of one head-image.
//  - project 8 V out-channels -> vh (global)
//  - project 8 K out-channels -> zero-padded LDS
//  - 5x5 conv partial over those 8 channels -> PLAIN store to ck4[cg]
// Conv phase (round 3): 1x4 output strips + aligned float4 LDS row reads.
//   thread -> (strip s = t>>2, channel-pair sub = t&3); each thread does
//   2 channels x (10 ds_read_b128 + 100 FMA), then 4-lane shfl_xor reduce
//   over sub. Replaces 200 ds_read_b32/thread with 20 ds_read_b128/thread
//   (2.5x fewer LDS bytes, 10x fewer LDS issue slots).
// -----------------------------------------------------------------------------
__global__ __launch_bounds__(256) void k_proj_conv(
    const float* __restrict__ kin, const float* __restrict__ vin,
    const float* __restrict__ wk, const float* __restrict__ bk,
    const float* __restrict__ wv, const float* __restrict__ bv,
    const float* __restrict__ wat,
    float* __restrict__ vh, float* __restrict__ ck4)
{
    const int bx  = blockIdx.x;
    const int img = bx >> 2;           // (b*NH + n)*LK + j
    const int cg  = bx & 3;            // channel group: 8 channels
    const int b   = img / (NH * LK);
    const int n   = (img / LK) % NH;
    const int j   = img % LK;
    const int hw  = threadIdx.x;
    const int h   = hw >> 4, w = hw & 15;

    __shared__ __attribute__((aligned(16))) float skh[8][CHPAD];

    for (int idx = hw; idx < 8 * CHPAD; idx += 256) ((float*)skh)[idx] = 0.f;

    const float* kb = kin + (size_t)((b * LK + j) * DF) * HW + hw;
    const float* vb = vin + (size_t)((b * LK + j) * DF) * HW + hw;

    float xr[DF];

    // ---- V projection: 8 out-channels of this group ----
    #pragma unroll
    for (int c = 0; c < DF; c++) xr[c] = vb[c * HW];
    #pragma unroll
    for (int d = 0; d < 8; d++) {
        const int o = n * DM + cg * 8 + d;
        const float* wr = wv + o * DF;
        float acc = bv[o];
        #pragma unroll
        for (int c = 0; c < DF; c++) acc += xr[c] * wr[c];
        vh[(size_t)img * (DM * HW) + (cg * 8 + d) * HW + hw] = lrelu(acc);
    }

    // ---- K projection into padded LDS ----
    #pragma unroll
    for (int c = 0; c < DF; c++) xr[c] = kb[c * HW];
    __syncthreads();   // zero-fill complete before interior writes
    #pragma unroll
    for (int d = 0; d < 8; d++) {
        const int o = n * DM + cg * 8 + d;
        const float* wr = wk + o * DF;
        float acc = bk[o];
        #pragma unroll
        for (int c = 0; c < DF; c++) acc += xr[c] * wr[c];
        skh[d][(h + 2) * PITCH + (w + 2)] = lrelu(acc);
    }
    __syncthreads();

    // ---- 5x5 conv partial over 8 channels, strip-vectorized ----
    // strip s covers output row r = s>>2, output cols wb..wb+3.
    // Needs padded rows r..r+4, padded cols wb..wb+7 (all within 20x24+pad,
    // zero-filled). float4 reads are 16B-aligned: (r+ky)*24 + wb == 0 mod 4.
    const int s   = hw >> 2;        // strip 0..63
    const int sub = hw & 3;         // channel-pair 0..3 (wave-varying, same wave)
    const int r   = s >> 2;         // output row 0..15
    const int wb  = (s & 3) << 2;   // output col base {0,4,8,12}

    float4 acc4 = make_float4(0.f, 0.f, 0.f, 0.f);
    #pragma unroll
    for (int cc = 0; cc < 2; cc++) {
        const int lc = sub * 2 + cc;
        const float* wc = wat + (cg * 8 + lc) * 25;
        #pragma unroll
        for (int ky = 0; ky < 5; ky++) {
            const float4 r0 = *(const float4*)&skh[lc][(r + ky) * PITCH + wb];
            const float4 r1 = *(const float4*)&skh[lc][(r + ky) * PITCH + wb + 4];
            const float rowv[8] = {r0.x, r0.y, r0.z, r0.w, r1.x, r1.y, r1.z, r1.w};
            #pragma unroll
            for (int kx = 0; kx < 5; kx++) {
                const float wv_ = wc[ky * 5 + kx];   // wave-uniform -> scalar load
                acc4.x += rowv[0 + kx] * wv_;
                acc4.y += rowv[1 + kx] * wv_;
                acc4.z += rowv[2 + kx] * wv_;
                acc4.w += rowv[3 + kx] * wv_;
            }
        }
    }
    // in-wave reduce over the 4 channel-pairs (lanes t, t^1, t^2 same strip)
    #pragma unroll
    for (int d = 1; d < 4; d <<= 1) {
        acc4.x += __shfl_xor(acc4.x, d);
        acc4.y += __shfl_xor(acc4.y, d);
        acc4.z += __shfl_xor(acc4.z, d);
        acc4.w += __shfl_xor(acc4.w, d);
    }
    if (sub == 0) {
        // hw index of strip start: r*16 + wb (16B-aligned), coalesced float4
        *(float4*)&ck4[(size_t)(cg * NIMG + img) * HW + r * 16 + wb] = acc4;
    }
}

// -----------------------------------------------------------------------------
// K2: grid 448 = (bn = b*NH+n) * 56 + u, 256 threads (1 thread/pixel).
//  - per-pixel softmax over j (24) from the 4 conv partials, in registers
//    (q-side conv + b_attn cancel in the softmax over keys)
//  - u <  24: write attn slice for query i=u (identical for all i)
//  - u >= 24: res channel c=u-24 = sum_j A[j] * vh[j,c]
// -----------------------------------------------------------------------------
__global__ __launch_bounds__(256) void k_softmax_res(
    const float* __restrict__ ck4, const float* __restrict__ vh,
    float* __restrict__ res, float* __restrict__ attn_out)
{
    const int bn = blockIdx.x / 56;   // 0..7
    const int u  = blockIdx.x % 56;   // 0..55
    const int hw = threadIdx.x;

    float e[LK];
    const float* c0 = ck4 + (size_t)(0 * NIMG + bn * LK) * HW + hw;
    const float* c1 = ck4 + (size_t)(1 * NIMG + bn * LK) * HW + hw;
    const float* c2 = ck4 + (size_t)(2 * NIMG + bn * LK) * HW + hw;
    const float* c3 = ck4 + (size_t)(3 * NIMG + bn * LK) * HW + hw;
    float m = -1e30f;
    #pragma unroll
    for (int jj = 0; jj < LK; jj++) {
        e[jj] = (c0[jj * HW] + c1[jj * HW]) + (c2[jj * HW] + c3[jj * HW]);
        m = fmaxf(m, e[jj]);
    }
    float s = 0.f;
    #pragma unroll
    for (int jj = 0; jj < LK; jj++) { e[jj] = __expf(e[jj] - m); s += e[jj]; }
    const float inv = 1.f / s;
    #pragma unroll
    for (int jj = 0; jj < LK; jj++) e[jj] *= inv;

    if (u < LQ) {
        // attn output for query i=u (same for every i)
        float* ao = attn_out + (size_t)((bn * LQ + u) * LK) * HW + hw;
        #pragma unroll
        for (int jj = 0; jj < LK; jj++) ao[jj * HW] = e[jj];
    } else {
        // res channel c = u - 24
        const int c = u - LQ;
        const float* vp = vh + (size_t)(bn * LK) * (DM * HW) + c * HW + hw;
        float acc = 0.f;
        #pragma unroll
        for (int jj = 0; jj < LK; jj++) acc += e[jj] * vp[(size_t)jj * DM * HW];
        res[(bn * DM + c) * HW + hw] = acc;
    }
}

// -----------------------------------------------------------------------------
// K3: final FC (128 -> 32), broadcast over l. grid 256 = b*128 + o*4 + lg,
// each block stores 6 of the 24 identical l-slices.
// -----------------------------------------------------------------------------
__global__ __launch_bounds__(256) void k_fc(
    const float* __restrict__ res, const float* __restrict__ wfc,
    float* __restrict__ out)
{
    const int bx = blockIdx.x;
    const int b  = bx >> 7;
    const int o  = (bx >> 2) & 31;
    const int lg = bx & 3;
    const int hw = threadIdx.x;

    const float* rp = res + (size_t)b * (NH * DM) * HW + hw;
    const float* wr = wfc + o * (NH * DM);
    float acc = 0.f;
    #pragma unroll
    for (int nc = 0; nc < NH * DM; nc++) acc += wr[nc] * rp[nc * HW];

    #pragma unroll
    for (int l = lg * 6; l < lg * 6 + 6; l++)
        out[(size_t)((b * LQ + l) * DM + o) * HW + hw] = acc;
}

// -----------------------------------------------------------------------------
extern "C" void kernel_launch(void* const* d_in, const int* in_sizes, int n_in,
                              void* d_out, int out_size, void* d_ws, size_t ws_size,
                              hipStream_t stream)
{
    // setup_inputs order: q,k,v,wq,bq,wk,bk,wv,bv,w_attn,b_attn,w_fc
    const float* k_in = (const float*)d_in[1];
    const float* v_in = (const float*)d_in[2];
    const float* wk   = (const float*)d_in[5];
    const float* bk   = (const float*)d_in[6];
    const float* wv   = (const float*)d_in[7];
    const float* bv   = (const float*)d_in[8];
    const float* wat  = (const float*)d_in[9];
    const float* wfc  = (const float*)d_in[11];
    // q, wq, bq, b_attn are provably unused (cancel in softmax over keys).

    float* out  = (float*)d_out;                       // (B,LQ,DM,H,W)
    float* attn = out + (size_t)BB * LQ * DM * HW;     // (B,NH,LQ,LK,1,H,W)

    float* vh  = (float*)d_ws;                                   // 1,572,864 f
    float* ck4 = vh  + (size_t)BB * NH * LK * DM * HW;           //   196,608 f
    float* res = ck4 + (size_t)4 * NIMG * HW;                    //    65,536 f
    // total ws use: ~7.3 MB

    hipLaunchKernelGGL(k_proj_conv, dim3(NIMG * 4), dim3(256), 0, stream,
                       k_in, v_in, wk, bk, wv, bv, wat, vh, ck4);
    hipLaunchKernelGGL(k_softmax_res, dim3(BB * NH * 56), dim3(256), 0, stream,
                       ck4, vh, res, attn);
    hipLaunchKernelGGL(k_fc, dim3(BB * DM * 4), dim3(256), 0, stream,
                       res, wfc, out);
}